// Round 1
// baseline (1445.460 us; speedup 1.0000x reference)
//
#include <hip/hip_runtime.h>
#include <hip/hip_bf16.h>

typedef __attribute__((ext_vector_type(8))) short short8;
typedef __attribute__((ext_vector_type(4))) short short4v;
typedef __attribute__((ext_vector_type(4))) float floatx4;

#define D128 128

__device__ __forceinline__ short f2bf(float f) {
    union { float f; unsigned u; } x; x.f = f;
    unsigned r = x.u + 0x7FFFu + ((x.u >> 16) & 1u);
    return (short)(r >> 16);
}

// ---- weight prep: per block, transpose one 128x128 fp32 W -> bf16 Wt[n][k] ----
__global__ void wprep_kernel(const float* Wq, const float* Wk, const float* Wv,
                             const float* We, const float* Ws, const float* W1,
                             const float* W2, short* wt) {
    const float* src;
    switch (blockIdx.x) {
        case 0: src = Wq; break;
        case 1: src = Wk; break;
        case 2: src = Wv; break;
        case 3: src = We; break;
        case 4: src = Ws; break;
        case 5: src = W1; break;
        default: src = W2; break;
    }
    short* dst = wt + (size_t)blockIdx.x * D128 * D128;
    for (int i = threadIdx.x; i < D128 * D128; i += blockDim.x) {
        int k = i >> 7, n = i & 127;
        dst[n * D128 + k] = f2bf(src[i]);
    }
}

// ---- GEMM: out[M x 128] = A[M x 128] @ W[128 x 128] (+bias) (+silu) ----
// Wt is bf16, pre-transposed: Wt[n*128 + k].
// Block: 256 thr (4 waves). Tile 64 rows x 128 cols, full K in LDS.
template <int EPI>  // 0: bias only, 1: bias + silu
__global__ __launch_bounds__(256) void gemm128(const float* __restrict__ A,
                                               const short* __restrict__ Wt,
                                               const float* __restrict__ bias,
                                               float* __restrict__ out, int M) {
    __shared__ __attribute__((aligned(16))) short As[64 * 136];
    __shared__ __attribute__((aligned(16))) short Bs[128 * 136];
    const int tid = threadIdx.x;
    const int row0 = blockIdx.x * 64;

    // stage A tile: 64x128 fp32 -> bf16 (8 float4 per thread)
#pragma unroll
    for (int it = 0; it < 8; ++it) {
        int i = it * 256 + tid;       // 0..2047 float4-groups
        int row = i >> 5, c4 = i & 31;
        float4 v = make_float4(0.f, 0.f, 0.f, 0.f);
        if (row0 + row < M)
            v = *(const float4*)(A + (size_t)(row0 + row) * D128 + c4 * 4);
        short4v s;
        s.x = f2bf(v.x); s.y = f2bf(v.y); s.z = f2bf(v.z); s.w = f2bf(v.w);
        *(short4v*)(&As[row * 136 + c4 * 4]) = s;
    }
    // stage B (whole 128x128 bf16 Wt, already [n][k])
    const short8* wp = (const short8*)Wt;
#pragma unroll
    for (int it = 0; it < 8; ++it) {
        int i = it * 256 + tid;       // 0..2047 short8-groups
        int n = i >> 4, kg = i & 15;
        *(short8*)(&Bs[n * 136 + kg * 8]) = wp[i];
    }
    __syncthreads();

    const int wv = tid >> 6, lane = tid & 63;
    const int m = lane & 15, quad = lane >> 4;
    const int rowbase = wv * 16;
    floatx4 acc[8];
#pragma unroll
    for (int t = 0; t < 8; ++t) acc[t] = (floatx4){0.f, 0.f, 0.f, 0.f};

#pragma unroll
    for (int kk = 0; kk < 4; ++kk) {
        int kq = kk * 32 + quad * 8;
        short8 af = *(const short8*)(&As[(rowbase + m) * 136 + kq]);
#pragma unroll
        for (int t = 0; t < 8; ++t) {
            short8 bf = *(const short8*)(&Bs[(t * 16 + m) * 136 + kq]);
            acc[t] = __builtin_amdgcn_mfma_f32_16x16x32_bf16(af, bf, acc[t], 0, 0, 0);
        }
    }

#pragma unroll
    for (int t = 0; t < 8; ++t) {
        int col = t * 16 + m;
        float bv = bias ? bias[col] : 0.f;
#pragma unroll
        for (int r = 0; r < 4; ++r) {
            int g = row0 + rowbase + quad * 4 + r;
            if (g < M) {
                float val = acc[t][r] + bv;
                if (EPI == 1) val = val / (1.f + __expf(-val));
                out[(size_t)g * D128 + col] = val;
            }
        }
    }
}

// ---- alpha: per (edge, head) dot(q[dst], k[src]+e) / 4, exp, denom atomicAdd ----
__global__ __launch_bounds__(256) void alpha_kernel(const int* __restrict__ ei,
                                                    const float* __restrict__ q,
                                                    const float* __restrict__ k,
                                                    const float* __restrict__ e,
                                                    float* __restrict__ ex,
                                                    float* __restrict__ denom, int E) {
    int t = threadIdx.x;
    size_t eid = (size_t)blockIdx.x * 2 + (t >> 7);
    if (eid >= (size_t)E) return;
    int idx = t & 127;
    int src = ei[eid], dst = ei[(size_t)E + eid];
    float p = q[(size_t)dst * D128 + idx] *
              (k[(size_t)src * D128 + idx] + e[eid * D128 + idx]);
    p += __shfl_xor(p, 1);
    p += __shfl_xor(p, 2);
    p += __shfl_xor(p, 4);
    p += __shfl_xor(p, 8);
    if ((idx & 15) == 0) {
        int h = idx >> 4;
        float v = __expf(p * 0.25f);
        ex[eid * 8 + h] = v;
        atomicAdd(&denom[(size_t)dst * 8 + h], v);
    }
}

// ---- msg: out[dst] += (ex/denom) * (v[src] + e) ----
__global__ __launch_bounds__(256) void msg_kernel(const int* __restrict__ ei,
                                                  const float* __restrict__ v,
                                                  const float* __restrict__ e,
                                                  const float* __restrict__ ex,
                                                  const float* __restrict__ denom,
                                                  float* __restrict__ outp, int E) {
    int t = threadIdx.x;
    size_t eid = (size_t)blockIdx.x * 2 + (t >> 7);
    if (eid >= (size_t)E) return;
    int idx = t & 127;
    int h = idx >> 4;
    int src = ei[eid], dst = ei[(size_t)E + eid];
    float w = ex[eid * 8 + h] / (denom[(size_t)dst * 8 + h] + 1e-16f);
    float val = w * (v[(size_t)src * D128 + idx] + e[eid * D128 + idx]);
    atomicAdd(&outp[(size_t)dst * D128 + idx], val);
}

// ---- h = x + LN(attn + skip); one wave per row ----
__global__ __launch_bounds__(256) void ln_h_kernel(const float* __restrict__ attn,
                                                   const float* __restrict__ skip,
                                                   const float* __restrict__ x,
                                                   const float* __restrict__ g,
                                                   const float* __restrict__ b,
                                                   float* __restrict__ h, int N) {
    int t = threadIdx.x;
    int r = blockIdx.x * 4 + (t >> 6);
    if (r >= N) return;
    int c0 = (t & 63) * 2;
    size_t base = (size_t)r * D128;
    float2 a = *(const float2*)(attn + base + c0);
    float2 s = *(const float2*)(skip + base + c0);
    float v0 = a.x + s.x, v1 = a.y + s.y;
    float sum = v0 + v1;
#pragma unroll
    for (int o = 32; o > 0; o >>= 1) sum += __shfl_xor(sum, o);
    float mu = sum * (1.f / 128.f);
    float d0 = v0 - mu, d1 = v1 - mu;
    float vs = d0 * d0 + d1 * d1;
#pragma unroll
    for (int o = 32; o > 0; o >>= 1) vs += __shfl_xor(vs, o);
    float rs = rsqrtf(vs * (1.f / 128.f) + 1e-5f);
    float2 xe = *(const float2*)(x + base + c0);
    float2 o2;
    o2.x = xe.x + d0 * rs * g[c0] + b[c0];
    o2.y = xe.y + d1 * rs * g[c0 + 1] + b[c0 + 1];
    *(float2*)(h + base + c0) = o2;
}

// ---- out = h + LN(ffn); one wave per row ----
__global__ __launch_bounds__(256) void ln_out_kernel(const float* __restrict__ ffn,
                                                     const float* __restrict__ h,
                                                     const float* __restrict__ g,
                                                     const float* __restrict__ b,
                                                     float* __restrict__ out, int N) {
    int t = threadIdx.x;
    int r = blockIdx.x * 4 + (t >> 6);
    if (r >= N) return;
    int c0 = (t & 63) * 2;
    size_t base = (size_t)r * D128;
    float2 f = *(const float2*)(ffn + base + c0);
    float v0 = f.x, v1 = f.y;
    float sum = v0 + v1;
#pragma unroll
    for (int o = 32; o > 0; o >>= 1) sum += __shfl_xor(sum, o);
    float mu = sum * (1.f / 128.f);
    float d0 = v0 - mu, d1 = v1 - mu;
    float vs = d0 * d0 + d1 * d1;
#pragma unroll
    for (int o = 32; o > 0; o >>= 1) vs += __shfl_xor(vs, o);
    float rs = rsqrtf(vs * (1.f / 128.f) + 1e-5f);
    float2 he = *(const float2*)(h + base + c0);
    float2 o2;
    o2.x = he.x + d0 * rs * g[c0] + b[c0];
    o2.y = he.y + d1 * rs * g[c0 + 1] + b[c0 + 1];
    *(float2*)(out + base + c0) = o2;
}

extern "C" void kernel_launch(void* const* d_in, const int* in_sizes, int n_in,
                              void* d_out, int out_size, void* d_ws, size_t ws_size,
                              hipStream_t stream) {
    const int*   ei    = (const int*)d_in[0];
    const float* x     = (const float*)d_in[1];
    const float* ea    = (const float*)d_in[2];
    const float* Wq    = (const float*)d_in[3];
    const float* bq    = (const float*)d_in[4];
    const float* Wk    = (const float*)d_in[5];
    const float* bk    = (const float*)d_in[6];
    const float* Wv    = (const float*)d_in[7];
    const float* bv    = (const float*)d_in[8];
    const float* We    = (const float*)d_in[9];
    const float* Wsk   = (const float*)d_in[10];
    const float* bskip = (const float*)d_in[11];
    const float* W1    = (const float*)d_in[12];
    const float* b1    = (const float*)d_in[13];
    const float* W2    = (const float*)d_in[14];
    const float* b2    = (const float*)d_in[15];
    const float* g1    = (const float*)d_in[16];
    const float* be1   = (const float*)d_in[17];
    const float* g2    = (const float*)d_in[18];
    const float* be2   = (const float*)d_in[19];

    const int N = in_sizes[1] / D128;
    const int E = in_sizes[2] / D128;
    const size_t nd = (size_t)N * D128;

    float* ws    = (float*)d_ws;
    float* q     = ws;                       // N*128
    float* k     = q + nd;                   // N*128
    float* v     = k + nd;                   // N*128
    float* skip  = v + nd;                   // N*128
    float* e     = skip + nd;                // E*128
    float* ex    = e + (size_t)E * D128;     // E*8
    float* denom = ex + (size_t)E * 8;       // N*8
    short* wt    = (short*)(denom + (size_t)N * 8);  // 7 * 128*128 bf16
    // reuse (lifetimes disjoint, stream-ordered):
    float* attn = q;   // zeroed after alpha_kernel, scatter target
    float* h    = k;   // written after alpha_kernel done with k
    float* t1   = v;   // written after msg_kernel done with v
    float* ffn  = e;   // written after msg_kernel done with e

    const int gN = (N + 63) / 64;
    const int gE = (E + 63) / 64;

    wprep_kernel<<<7, 256, 0, stream>>>(Wq, Wk, Wv, We, Wsk, W1, W2, wt);

    gemm128<0><<<gN, 256, 0, stream>>>(x, wt + 0 * 16384, bq, q, N);
    gemm128<0><<<gN, 256, 0, stream>>>(x, wt + 1 * 16384, bk, k, N);
    gemm128<0><<<gN, 256, 0, stream>>>(x, wt + 2 * 16384, bv, v, N);
    gemm128<0><<<gE, 256, 0, stream>>>(ea, wt + 3 * 16384, nullptr, e, E);
    gemm128<0><<<gN, 256, 0, stream>>>(x, wt + 4 * 16384, bskip, skip, N);

    hipMemsetAsync(denom, 0, (size_t)N * 8 * sizeof(float), stream);
    alpha_kernel<<<(E + 1) / 2, 256, 0, stream>>>(ei, q, k, e, ex, denom, E);
    hipMemsetAsync(attn, 0, nd * sizeof(float), stream);
    msg_kernel<<<(E + 1) / 2, 256, 0, stream>>>(ei, v, e, ex, denom, attn, E);

    ln_h_kernel<<<(N + 3) / 4, 256, 0, stream>>>(attn, skip, x, g1, be1, h, N);
    gemm128<1><<<gN, 256, 0, stream>>>(h, wt + 5 * 16384, b1, t1, N);
    gemm128<0><<<gN, 256, 0, stream>>>(t1, wt + 6 * 16384, b2, ffn, N);
    ln_out_kernel<<<(N + 3) / 4, 256, 0, stream>>>(ffn, h, g2, be2, (float*)d_out, N);
}

// Round 2
// 1067.697 us; speedup vs baseline: 1.3538x; 1.3538x over previous
//
#include <hip/hip_runtime.h>
#include <hip/hip_bf16.h>

typedef __attribute__((ext_vector_type(8))) short short8;
typedef __attribute__((ext_vector_type(4))) short short4v;
typedef __attribute__((ext_vector_type(4))) float floatx4;

#define D128 128

__device__ __forceinline__ short f2bf(float f) {
    union { float f; unsigned u; } x; x.f = f;
    unsigned r = x.u + 0x7FFFu + ((x.u >> 16) & 1u);
    return (short)(r >> 16);
}
__device__ __forceinline__ float bflo(unsigned u) { return __uint_as_float(u << 16); }
__device__ __forceinline__ float bfhi(unsigned u) { return __uint_as_float(u & 0xffff0000u); }

// ---- weight prep: per block, transpose one 128x128 fp32 W -> bf16 Wt[n][k] ----
__global__ void wprep_kernel(const float* Wq, const float* Wk, const float* Wv,
                             const float* We, const float* Ws, const float* W1,
                             const float* W2, short* wt) {
    const float* src;
    switch (blockIdx.x) {
        case 0: src = Wq; break;
        case 1: src = Wk; break;
        case 2: src = Wv; break;
        case 3: src = We; break;
        case 4: src = Ws; break;
        case 5: src = W1; break;
        default: src = W2; break;
    }
    short* dst = wt + (size_t)blockIdx.x * D128 * D128;
    for (int i = threadIdx.x; i < D128 * D128; i += blockDim.x) {
        int k = i >> 7, n = i & 127;
        dst[n * D128 + k] = f2bf(src[i]);
    }
}

// ---- GEMM: out[M x 128] = A[M x 128] @ W[128 x 128] (+bias) (+silu) ----
// TA: float (fp32 A) or short (bf16 A). TO: float or short (bf16 out).
template <typename TA, typename TO, int SILU>
__global__ __launch_bounds__(256) void gemm128(const TA* __restrict__ A,
                                               const short* __restrict__ Wt,
                                               const float* __restrict__ bias,
                                               TO* __restrict__ out, int M) {
    __shared__ __attribute__((aligned(16))) short As[64 * 136];
    __shared__ __attribute__((aligned(16))) short Bs[128 * 136];
    const int tid = threadIdx.x;
    const int row0 = blockIdx.x * 64;

    if constexpr (sizeof(TA) == 4) {
#pragma unroll
        for (int it = 0; it < 8; ++it) {
            int i = it * 256 + tid;
            int row = i >> 5, c4 = i & 31;
            float4 v = make_float4(0.f, 0.f, 0.f, 0.f);
            if (row0 + row < M)
                v = *(const float4*)((const float*)A + (size_t)(row0 + row) * D128 + c4 * 4);
            short4v s;
            s.x = f2bf(v.x); s.y = f2bf(v.y); s.z = f2bf(v.z); s.w = f2bf(v.w);
            *(short4v*)(&As[row * 136 + c4 * 4]) = s;
        }
    } else {
#pragma unroll
        for (int it = 0; it < 4; ++it) {
            int i = it * 256 + tid;
            int row = i >> 4, kg = i & 15;
            short8 s;
#pragma unroll
            for (int j = 0; j < 8; ++j) s[j] = 0;
            if (row0 + row < M)
                s = *(const short8*)((const short*)A + (size_t)(row0 + row) * D128 + kg * 8);
            *(short8*)(&As[row * 136 + kg * 8]) = s;
        }
    }
    const short8* wp = (const short8*)Wt;
#pragma unroll
    for (int it = 0; it < 8; ++it) {
        int i = it * 256 + tid;
        int n = i >> 4, kg = i & 15;
        *(short8*)(&Bs[n * 136 + kg * 8]) = wp[i];
    }
    __syncthreads();

    const int wv = tid >> 6, lane = tid & 63;
    const int m = lane & 15, quad = lane >> 4;
    const int rowbase = wv * 16;
    floatx4 acc[8];
#pragma unroll
    for (int t = 0; t < 8; ++t) acc[t] = (floatx4){0.f, 0.f, 0.f, 0.f};

#pragma unroll
    for (int kk = 0; kk < 4; ++kk) {
        int kq = kk * 32 + quad * 8;
        short8 af = *(const short8*)(&As[(rowbase + m) * 136 + kq]);
#pragma unroll
        for (int t = 0; t < 8; ++t) {
            short8 bf = *(const short8*)(&Bs[(t * 16 + m) * 136 + kq]);
            acc[t] = __builtin_amdgcn_mfma_f32_16x16x32_bf16(af, bf, acc[t], 0, 0, 0);
        }
    }

#pragma unroll
    for (int t = 0; t < 8; ++t) {
        int col = t * 16 + m;
        float bv = bias ? bias[col] : 0.f;
#pragma unroll
        for (int r = 0; r < 4; ++r) {
            int g = row0 + rowbase + quad * 4 + r;
            if (g < M) {
                float val = acc[t][r] + bv;
                if (SILU) val = val / (1.f + __expf(-val));
                if constexpr (sizeof(TO) == 4)
                    out[(size_t)g * D128 + col] = val;
                else
                    out[(size_t)g * D128 + col] = f2bf(val);
            }
        }
    }
}

// ---- CSR build ----
__global__ void hist_kernel(const int* __restrict__ ei, int* __restrict__ deg, int E) {
    int i = blockIdx.x * 256 + threadIdx.x;
    if (i < E) atomicAdd(&deg[ei[(size_t)E + i]], 1);
}

__global__ __launch_bounds__(256) void scan_a(const int* __restrict__ deg,
                                              int* __restrict__ rowstart,
                                              int* __restrict__ partials, int N) {
    __shared__ int lds[256];
    int base = blockIdx.x * 1024;
    int t = threadIdx.x;
    int v[4];
    int s = 0;
#pragma unroll
    for (int j = 0; j < 4; ++j) {
        int i = base + t * 4 + j;
        v[j] = (i < N) ? deg[i] : 0;
        s += v[j];
    }
    lds[t] = s;
    __syncthreads();
    int val = s;
    for (int off = 1; off < 256; off <<= 1) {
        int other = (t >= off) ? lds[t - off] : 0;
        __syncthreads();
        val += other;
        lds[t] = val;
        __syncthreads();
    }
    int excl = val - s;
#pragma unroll
    for (int j = 0; j < 4; ++j) {
        int i = base + t * 4 + j;
        if (i < N) rowstart[i] = excl;
        excl += v[j];
    }
    if (t == 255) partials[blockIdx.x] = val;
}

__global__ __launch_bounds__(256) void scan_b(int* __restrict__ partials, int n) {
    __shared__ int lds[256];
    int t = threadIdx.x;
    int s = (t < n) ? partials[t] : 0;
    lds[t] = s;
    __syncthreads();
    int val = s;
    for (int off = 1; off < 256; off <<= 1) {
        int other = (t >= off) ? lds[t - off] : 0;
        __syncthreads();
        val += other;
        lds[t] = val;
        __syncthreads();
    }
    if (t < n) partials[t] = val - s;
}

__global__ void scan_c(int* __restrict__ rowstart, const int* __restrict__ partials,
                       int N, int Etot) {
    int i = blockIdx.x * 256 + threadIdx.x;
    if (i < N) rowstart[i] += partials[i >> 10];
    if (i == 0) rowstart[N] = Etot;
}

__global__ void fill_kernel(const int* __restrict__ ei, int* __restrict__ cursor,
                            int2* __restrict__ cst, int E) {
    int i = blockIdx.x * 256 + threadIdx.x;
    if (i >= E) return;
    int src = ei[i], dst = ei[(size_t)E + i];
    int slot = atomicAdd(&cursor[dst], 1);
    cst[slot] = make_int2(src, i);
}

// ---- fused attention gather: per node, single pass over incoming edges ----
// out[i] = sum_j exp(q_i.(k_j+e_j)/4) * (v_j+e_j) / (sum_j exp(...) + 1e-16)
// 64 lanes per node (1 wave), 2 cols/lane; head = 8 consecutive lanes.
__global__ __launch_bounds__(256) void attn_gather(const int* __restrict__ rowstart,
                                                   const int2* __restrict__ cst,
                                                   const unsigned* __restrict__ q2,
                                                   const unsigned* __restrict__ k2,
                                                   const unsigned* __restrict__ v2,
                                                   const unsigned* __restrict__ e2,
                                                   float* __restrict__ attn, int N) {
    int t = threadIdx.x;
    int node = blockIdx.x * 4 + (t >> 6);
    if (node >= N) return;
    int l = t & 63;
    unsigned qu = q2[(size_t)node * 64 + l];
    float q0 = bflo(qu), q1 = bfhi(qu);
    int p0 = rowstart[node], p1 = rowstart[node + 1];
    float num0 = 0.f, num1 = 0.f, den = 0.f;
    for (int p = p0; p < p1; ++p) {
        int2 se = cst[p];
        unsigned ku = k2[(size_t)se.x * 64 + l];
        unsigned eu = e2[(size_t)se.y * 64 + l];
        unsigned vu = v2[(size_t)se.x * 64 + l];
        float ke0 = bflo(ku) + bflo(eu), ke1 = bfhi(ku) + bfhi(eu);
        float pd = q0 * ke0 + q1 * ke1;
        pd += __shfl_xor(pd, 1);
        pd += __shfl_xor(pd, 2);
        pd += __shfl_xor(pd, 4);
        float ex = __expf(pd * 0.25f);
        den += ex;
        num0 += ex * (bflo(vu) + bflo(eu));
        num1 += ex * (bfhi(vu) + bfhi(eu));
    }
    float inv = 1.f / (den + 1e-16f);
    float2 o;
    o.x = num0 * inv;
    o.y = num1 * inv;
    *(float2*)(attn + (size_t)node * D128 + l * 2) = o;
}

// ---- h = x + LN(attn + skip); one wave per row (skip is bf16) ----
__global__ __launch_bounds__(256) void ln_h_kernel(const float* __restrict__ attn,
                                                   const unsigned* __restrict__ skip2,
                                                   const float* __restrict__ x,
                                                   const float* __restrict__ g,
                                                   const float* __restrict__ b,
                                                   float* __restrict__ h, int N) {
    int t = threadIdx.x;
    int r = blockIdx.x * 4 + (t >> 6);
    if (r >= N) return;
    int l = t & 63;
    int c0 = l * 2;
    size_t base = (size_t)r * D128;
    float2 a = *(const float2*)(attn + base + c0);
    unsigned su = skip2[(size_t)r * 64 + l];
    float v0 = a.x + bflo(su), v1 = a.y + bfhi(su);
    float sum = v0 + v1;
#pragma unroll
    for (int o = 32; o > 0; o >>= 1) sum += __shfl_xor(sum, o);
    float mu = sum * (1.f / 128.f);
    float d0 = v0 - mu, d1 = v1 - mu;
    float vs = d0 * d0 + d1 * d1;
#pragma unroll
    for (int o = 32; o > 0; o >>= 1) vs += __shfl_xor(vs, o);
    float rs = rsqrtf(vs * (1.f / 128.f) + 1e-5f);
    float2 xe = *(const float2*)(x + base + c0);
    float2 o2;
    o2.x = xe.x + d0 * rs * g[c0] + b[c0];
    o2.y = xe.y + d1 * rs * g[c0 + 1] + b[c0 + 1];
    *(float2*)(h + base + c0) = o2;
}

// ---- out = h + LN(ffn); one wave per row ----
__global__ __launch_bounds__(256) void ln_out_kernel(const float* __restrict__ ffn,
                                                     const float* __restrict__ h,
                                                     const float* __restrict__ g,
                                                     const float* __restrict__ b,
                                                     float* __restrict__ out, int N) {
    int t = threadIdx.x;
    int r = blockIdx.x * 4 + (t >> 6);
    if (r >= N) return;
    int c0 = (t & 63) * 2;
    size_t base = (size_t)r * D128;
    float2 f = *(const float2*)(ffn + base + c0);
    float v0 = f.x, v1 = f.y;
    float sum = v0 + v1;
#pragma unroll
    for (int o = 32; o > 0; o >>= 1) sum += __shfl_xor(sum, o);
    float mu = sum * (1.f / 128.f);
    float d0 = v0 - mu, d1 = v1 - mu;
    float vs = d0 * d0 + d1 * d1;
#pragma unroll
    for (int o = 32; o > 0; o >>= 1) vs += __shfl_xor(vs, o);
    float rs = rsqrtf(vs * (1.f / 128.f) + 1e-5f);
    float2 he = *(const float2*)(h + base + c0);
    float2 o2;
    o2.x = he.x + d0 * rs * g[c0] + b[c0];
    o2.y = he.y + d1 * rs * g[c0 + 1] + b[c0 + 1];
    *(float2*)(out + base + c0) = o2;
}

extern "C" void kernel_launch(void* const* d_in, const int* in_sizes, int n_in,
                              void* d_out, int out_size, void* d_ws, size_t ws_size,
                              hipStream_t stream) {
    const int*   ei    = (const int*)d_in[0];
    const float* x     = (const float*)d_in[1];
    const float* ea    = (const float*)d_in[2];
    const float* Wq    = (const float*)d_in[3];
    const float* bq    = (const float*)d_in[4];
    const float* Wk    = (const float*)d_in[5];
    const float* bk    = (const float*)d_in[6];
    const float* Wv    = (const float*)d_in[7];
    const float* bv    = (const float*)d_in[8];
    const float* We    = (const float*)d_in[9];
    const float* Wsk   = (const float*)d_in[10];
    const float* bskip = (const float*)d_in[11];
    const float* W1    = (const float*)d_in[12];
    const float* b1    = (const float*)d_in[13];
    const float* W2    = (const float*)d_in[14];
    const float* b2    = (const float*)d_in[15];
    const float* g1    = (const float*)d_in[16];
    const float* be1   = (const float*)d_in[17];
    const float* g2    = (const float*)d_in[18];
    const float* be2   = (const float*)d_in[19];

    const int N = in_sizes[1] / D128;
    const int E = in_sizes[2] / D128;
    const size_t nd = (size_t)N * D128;
    const size_t ed = (size_t)E * D128;

    char* p = (char*)d_ws;
    auto alloc = [&](size_t bytes) {
        char* r = p;
        p += (bytes + 255) & ~(size_t)255;
        return (void*)r;
    };
    short* qb       = (short*)alloc(nd * 2);
    short* kb       = (short*)alloc(nd * 2);
    short* vb       = (short*)alloc(nd * 2);
    short* sb       = (short*)alloc(nd * 2);   // skip
    short* ebuf     = (short*)alloc(ed * 2);
    float* attn     = (float*)alloc(nd * 4);
    float* h        = (float*)alloc(nd * 4);
    short* t1b      = (short*)alloc(nd * 2);
    float* ffn      = (float*)alloc(nd * 4);
    short* wt       = (short*)alloc(7 * 16384 * 2);
    int*   deg      = (int*)alloc((size_t)N * 4);
    int*   rowstart = (int*)alloc(((size_t)N + 1) * 4);
    int*   partials = (int*)alloc(512 * 4);
    int*   cursor   = (int*)alloc((size_t)N * 4);
    int2*  cst      = (int2*)alloc((size_t)E * 8);

    const int gN = (N + 63) / 64;
    const int gE = (E + 63) / 64;
    const int nchunks = (N + 1023) / 1024;

    wprep_kernel<<<7, 256, 0, stream>>>(Wq, Wk, Wv, We, Wsk, W1, W2, wt);

    // CSR build (by dst)
    hipMemsetAsync(deg, 0, (size_t)N * 4, stream);
    hist_kernel<<<(E + 255) / 256, 256, 0, stream>>>(ei, deg, E);
    scan_a<<<nchunks, 256, 0, stream>>>(deg, rowstart, partials, N);
    scan_b<<<1, 256, 0, stream>>>(partials, nchunks);
    scan_c<<<(N + 255) / 256, 256, 0, stream>>>(rowstart, partials, N, E);
    hipMemcpyAsync(cursor, rowstart, (size_t)N * 4, hipMemcpyDeviceToDevice, stream);
    fill_kernel<<<(E + 255) / 256, 256, 0, stream>>>(ei, cursor, cst, E);

    // projections (bf16 outputs)
    gemm128<float, short, 0><<<gN, 256, 0, stream>>>(x, wt + 0 * 16384, bq, qb, N);
    gemm128<float, short, 0><<<gN, 256, 0, stream>>>(x, wt + 1 * 16384, bk, kb, N);
    gemm128<float, short, 0><<<gN, 256, 0, stream>>>(x, wt + 2 * 16384, bv, vb, N);
    gemm128<float, short, 0><<<gN, 256, 0, stream>>>(x, wt + 4 * 16384, bskip, sb, N);
    gemm128<float, short, 0><<<gE, 256, 0, stream>>>(ea, wt + 3 * 16384, nullptr, ebuf, E);

    // fused attention (atomic-free gather)
    attn_gather<<<(N + 3) / 4, 256, 0, stream>>>(rowstart, cst, (const unsigned*)qb,
                                                 (const unsigned*)kb, (const unsigned*)vb,
                                                 (const unsigned*)ebuf, attn, N);

    ln_h_kernel<<<(N + 3) / 4, 256, 0, stream>>>(attn, (const unsigned*)sb, x, g1, be1, h, N);
    gemm128<float, short, 1><<<gN, 256, 0, stream>>>(h, wt + 5 * 16384, b1, t1b, N);
    gemm128<short, float, 0><<<gN, 256, 0, stream>>>(t1b, wt + 6 * 16384, b2, ffn, N);
    ln_out_kernel<<<(N + 3) / 4, 256, 0, stream>>>(ffn, h, g2, be2, (float*)d_out, N);
}